// Round 1
// baseline (15586.830 us; speedup 1.0000x reference)
//
#include <hip/hip_runtime.h>
#include <cstddef>

#define TT 4096
#define BB 64
#define HD 128
#define G4 512
#define FD 40
#define NCLS 12
#define CH 512
#define NCHUNK 8

__device__ __forceinline__ float sigf(float x){ return 1.0f/(1.0f + __expf(-x)); }
__device__ __forceinline__ float tanh_f(float x){ return 1.0f - 2.0f/(__expf(2.0f*x) + 1.0f); }

// transpose W_hh [512][128] -> [128][512] so REC weight preload is coalesced
__global__ void whh_transpose(const float* __restrict__ W, float* __restrict__ WT){
  int idx = blockIdx.x*256 + threadIdx.x;   // 65536 elements
  int k = idx >> 9;
  int j = idx & 511;
  WT[idx] = W[j*HD + k];
}

// Persistent recurrence: one block per batch element, 256 threads.
// Thread t owns gate rows j=t and j=t+256; W_hh rows held in VGPRs.
__global__ __launch_bounds__(256, 1)
void lstm_rec(const float* __restrict__ pre,   // [nsteps][64][512] pre-gates (x*Wih + b_ih + b_hh)
              const float* __restrict__ WT,    // [128][512] transposed W_hh
              float* __restrict__ hout,        // [nsteps][64][128]
              float* __restrict__ state,       // [64][2][128] (h, c)
              int nsteps)
{
  const int b = blockIdx.x;
  const int t = threadIdx.x;
  __shared__ __align__(16) float h_lds[HD];
  __shared__ __align__(16) float g_lds[G4];
  float w0[HD], w1[HD];
#pragma unroll
  for (int k=0;k<HD;k++){                 // fully unrolled -> static reg indices
    w0[k] = WT[k*G4 + t];
    w1[k] = WT[k*G4 + t + 256];
  }
  float c = 0.0f;
  if (t < HD){
    h_lds[t] = state[b*256 + t];
    c = state[b*256 + 128 + t];
  }
  __syncthreads();
  const float* prep = pre + b*G4 + t;
  float pg0 = prep[0];
  float pg1 = prep[256];
  for (int s=0; s<nsteps; ++s){
    int sn = (s+1 < nsteps) ? (s+1) : s;
    float npg0 = prep[(size_t)sn*(BB*G4)];        // prefetch next step's pre-gates
    float npg1 = prep[(size_t)sn*(BB*G4) + 256];
    float acc0 = pg0, acc1 = pg1;
#pragma unroll
    for (int k=0;k<HD;k+=4){
      float4 hv = *(const float4*)&h_lds[k];      // uniform-address broadcast read
      acc0 = fmaf(hv.x, w0[k+0], acc0);
      acc1 = fmaf(hv.x, w1[k+0], acc1);
      acc0 = fmaf(hv.y, w0[k+1], acc0);
      acc1 = fmaf(hv.y, w1[k+1], acc1);
      acc0 = fmaf(hv.z, w0[k+2], acc0);
      acc1 = fmaf(hv.z, w1[k+2], acc1);
      acc0 = fmaf(hv.w, w0[k+3], acc0);
      acc1 = fmaf(hv.w, w1[k+3], acc1);
    }
    g_lds[t] = acc0;
    g_lds[t+256] = acc1;
    __syncthreads();
    if (t < HD){
      float gi = g_lds[t];
      float gf = g_lds[t+128];
      float gg = g_lds[t+256];
      float go = g_lds[t+384];
      c = sigf(gf)*c + sigf(gi)*tanh_f(gg);
      float h = sigf(go)*tanh_f(c);
      h_lds[t] = h;
      hout[((size_t)s*BB + b)*HD + t] = h;
    }
    __syncthreads();
    pg0 = npg0;
    pg1 = npg1;
  }
  if (t < HD){
    state[b*256 + t] = h_lds[t];
    state[b*256 + 128 + t] = c;
  }
}

// Generic fp32 tiled GEMM: C[M x N] = A[M x K] * B(^T) + bias, tile 128x128x8, 8x8/thread.
// AMODE: 0 -> A row-major lda=KD; 1 -> A is x with layout [64][4096][40], row m=(t_local*64+b)
// BTRANS: 1 -> Bw is [N][K] (C=A*W^T); 0 -> Bw is [K][N]
// EPI: 0 -> C[m][n]=acc+b1[n]+b2[n] (N=512); 1 -> attn[m]=sum_n tanh(acc+b1[n])*b2[n] (N=128)
template<int AMODE, int BTRANS, int KD, int EPI>
__global__ __launch_bounds__(256)
void gemm_k(const float* __restrict__ A, const float* __restrict__ Bw,
            const float* __restrict__ b1, const float* __restrict__ b2,
            float* __restrict__ C, int t0)
{
  const int tid = threadIdx.x;
  const int tx = tid & 15, ty = tid >> 4;
  const int m0 = blockIdx.x * 128;
  const int n0 = blockIdx.y * 128;
  const int NDIM = EPI ? 128 : 512;
  __shared__ __align__(16) float Ast[8*128];
  __shared__ __align__(16) float Bst[8*128];
  __shared__ float red[128*17];
  float acc[8][8];
#pragma unroll
  for (int i=0;i<8;i++)
#pragma unroll
    for (int j=0;j<8;j++) acc[i][j]=0.f;

  const int NK = KD/8;
  for (int kt=0; kt<NK; ++kt){
    const int k0 = kt*8;
    const int arow = tid >> 1;
    const int akq = (tid & 1) * 4;
    const float* aptr;
    if (AMODE == 0){
      aptr = A + (size_t)(m0 + arow)*KD + k0 + akq;
    } else {
      int m = m0 + arow;
      int bidx = m & 63;
      int trow = t0 + (m >> 6);
      aptr = A + ((size_t)bidx*TT + trow)*FD + k0 + akq;
    }
    float4 av = *(const float4*)aptr;
    float4 bv;
    int brow, bkq;
    if (BTRANS){
      brow = tid >> 1; bkq = (tid & 1) * 4;
      bv = *(const float4*)(Bw + (size_t)(n0 + brow)*KD + k0 + bkq);
    } else {
      brow = tid >> 5;
      bkq = (tid & 31) * 4;
      bv = *(const float4*)(Bw + (size_t)(k0 + brow)*NDIM + n0 + bkq);
    }
    __syncthreads();
    Ast[(akq+0)*128 + arow] = av.x;
    Ast[(akq+1)*128 + arow] = av.y;
    Ast[(akq+2)*128 + arow] = av.z;
    Ast[(akq+3)*128 + arow] = av.w;
    if (BTRANS){
      Bst[(bkq+0)*128 + brow] = bv.x;
      Bst[(bkq+1)*128 + brow] = bv.y;
      Bst[(bkq+2)*128 + brow] = bv.z;
      Bst[(bkq+3)*128 + brow] = bv.w;
    } else {
      *(float4*)&Bst[brow*128 + bkq] = bv;
    }
    __syncthreads();
#pragma unroll
    for (int kk=0; kk<8; ++kk){
      float a[8], bbv[8];
      *(float4*)&a[0]   = *(const float4*)&Ast[kk*128 + ty*8];
      *(float4*)&a[4]   = *(const float4*)&Ast[kk*128 + ty*8 + 4];
      *(float4*)&bbv[0] = *(const float4*)&Bst[kk*128 + tx*8];
      *(float4*)&bbv[4] = *(const float4*)&Bst[kk*128 + tx*8 + 4];
#pragma unroll
      for (int i=0;i<8;i++)
#pragma unroll
        for (int j=0;j<8;j++) acc[i][j] = fmaf(a[i], bbv[j], acc[i][j]);
    }
  }
  if (EPI == 0){
    const int nb = n0 + tx*8;
    float bias[8];
#pragma unroll
    for (int j=0;j<8;j++) bias[j] = b1[nb+j] + b2[nb+j];
#pragma unroll
    for (int i=0;i<8;i++){
      int m = m0 + ty*8 + i;
      float* cp = C + (size_t)m*NDIM + nb;
      float4 o0 = make_float4(acc[i][0]+bias[0], acc[i][1]+bias[1], acc[i][2]+bias[2], acc[i][3]+bias[3]);
      float4 o1 = make_float4(acc[i][4]+bias[4], acc[i][5]+bias[5], acc[i][6]+bias[6], acc[i][7]+bias[7]);
      *(float4*)&cp[0] = o0;
      *(float4*)&cp[4] = o1;
    }
  } else {
    const int nb = tx*8;
    float bias[8], proj[8];
#pragma unroll
    for (int j=0;j<8;j++){ bias[j] = b1[nb+j]; proj[j] = b2[nb+j]; }
#pragma unroll
    for (int i=0;i<8;i++){
      float p = 0.f;
#pragma unroll
      for (int j=0;j<8;j++) p += tanh_f(acc[i][j] + bias[j]) * proj[j];
      red[(ty*8+i)*17 + tx] = p;
    }
    __syncthreads();
    if (tid < 128){
      float s = 0.f;
#pragma unroll
      for (int xx=0; xx<16; ++xx) s += red[tid*17 + xx];
      C[m0 + tid] = s;
    }
  }
}

// softmax over time per batch column; attn layout [T][B]
__global__ void softmax_t(float* __restrict__ attn){
  const int b = blockIdx.x;
  const int tid = threadIdx.x;   // 256
  __shared__ float red[256];
  float v[16];
  float m = -1e30f;
#pragma unroll
  for (int i=0;i<16;i++){
    v[i] = attn[(i*256 + tid)*BB + b];
    m = fmaxf(m, v[i]);
  }
  red[tid] = m; __syncthreads();
  for (int s=128; s>0; s>>=1){ if (tid < s) red[tid] = fmaxf(red[tid], red[tid+s]); __syncthreads(); }
  m = red[0]; __syncthreads();
  float sum = 0.f;
#pragma unroll
  for (int i=0;i<16;i++){ v[i] = __expf(v[i]-m); sum += v[i]; }
  red[tid] = sum; __syncthreads();
  for (int s=128; s>0; s>>=1){ if (tid < s) red[tid] += red[tid+s]; __syncthreads(); }
  float inv = 1.0f/red[0];
#pragma unroll
  for (int i=0;i<16;i++) attn[(i*256 + tid)*BB + b] = v[i]*inv;
}

// ctx partial: block (b, g): partial over 512 timesteps
__global__ void ctx_k(const float* __restrict__ attn, const float* __restrict__ h1,
                      float* __restrict__ ctxp){
  const int b = blockIdx.x;
  const int g = blockIdx.y;
  const int h = threadIdx.x;   // 128
  float acc = 0.f;
  const int tb = g*512;
#pragma unroll 4
  for (int i=0;i<512;i++){
    int t = tb + i;
    acc = fmaf(attn[t*BB + b], h1[((size_t)t*BB + b)*HD + h], acc);
  }
  ctxp[((size_t)b*8 + g)*HD + h] = acc;
}

__global__ void head_k(const float* __restrict__ ctxp, const float* __restrict__ d1w,
                       const float* __restrict__ d1b, const float* __restrict__ ow,
                       const float* __restrict__ ob, float* __restrict__ out){
  const int b = blockIdx.x;
  const int tid = threadIdx.x;  // 64
  __shared__ float cl[128];
  __shared__ float yl[64];
  for (int i=tid; i<128; i+=64){
    float s = 0.f;
#pragma unroll
    for (int g=0; g<8; g++) s += ctxp[((size_t)b*8 + g)*HD + i];
    cl[i] = s;
  }
  __syncthreads();
  float y = d1b[tid];
#pragma unroll 8
  for (int k=0;k<128;k++) y = fmaf(cl[k], d1w[tid*128 + k], y);
  yl[tid] = y;
  __syncthreads();
  if (tid < NCLS){
    float o = ob[tid];
#pragma unroll 8
    for (int j=0;j<64;j++) o = fmaf(yl[j], ow[tid*64 + j], o);
    out[b*NCLS + tid] = o;
  }
}

extern "C" void kernel_launch(void* const* d_in, const int* in_sizes, int n_in,
                              void* d_out, int out_size, void* d_ws, size_t ws_size,
                              hipStream_t stream) {
  const float* x     = (const float*)d_in[0];
  const float* Wih0  = (const float*)d_in[1];
  const float* Whh0  = (const float*)d_in[2];
  const float* bih0  = (const float*)d_in[3];
  const float* bhh0  = (const float*)d_in[4];
  const float* Wih1  = (const float*)d_in[5];
  const float* Whh1  = (const float*)d_in[6];
  const float* bih1  = (const float*)d_in[7];
  const float* bhh1  = (const float*)d_in[8];
  const float* wW    = (const float*)d_in[9];
  const float* bias  = (const float*)d_in[10];
  const float* proj  = (const float*)d_in[11];
  const float* d1w   = (const float*)d_in[12];
  const float* d1b   = (const float*)d_in[13];
  const float* ow    = (const float*)d_in[14];
  const float* ob    = (const float*)d_in[15];

  float* ws = (float*)d_ws;
  float* state0 = ws;                          // 64*256
  float* state1 = state0 + 16384;              // 64*256
  float* whhT0  = state1 + 16384;              // 128*512
  float* whhT1  = whhT0 + 65536;               // 128*512
  float* pre    = whhT1 + 65536;               // CH*64*512 = 16.78M
  float* h0c    = pre + (size_t)CH*BB*G4;      // CH*64*128 = 4.19M
  float* h1     = h0c + (size_t)CH*BB*HD;      // T*64*128 = 33.55M
  float* attn   = h1 + (size_t)TT*BB*HD;       // T*64
  float* ctxp   = attn + (size_t)TT*BB;        // 64*8*128

  hipMemsetAsync(state0, 0, 2*16384*sizeof(float), stream);
  whh_transpose<<<256, 256, 0, stream>>>(Whh0, whhT0);
  whh_transpose<<<256, 256, 0, stream>>>(Whh1, whhT1);

  for (int c=0; c<NCHUNK; ++c){
    int t0 = c*CH;
    // layer0 pre-gates: x @ Wih0^T + bih0 + bhh0
    gemm_k<1,1,40,0><<<dim3(CH*BB/128, 4), 256, 0, stream>>>(x, Wih0, bih0, bhh0, pre, t0);
    lstm_rec<<<64, 256, 0, stream>>>(pre, whhT0, h0c, state0, CH);
    // layer1 pre-gates: h0 @ Wih1^T + bih1 + bhh1
    gemm_k<0,1,128,0><<<dim3(CH*BB/128, 4), 256, 0, stream>>>(h0c, Wih1, bih1, bhh1, pre, 0);
    lstm_rec<<<64, 256, 0, stream>>>(pre, whhT1, h1 + (size_t)t0*BB*HD, state1, CH);
  }

  // attention scores: attn[m] = sum_k tanh((h1 @ wW)[m,k] + bias[k]) * proj[k]
  gemm_k<0,0,128,1><<<dim3(TT*BB/128, 1), 256, 0, stream>>>(h1, wW, bias, proj, attn, 0);
  softmax_t<<<64, 256, 0, stream>>>(attn);
  ctx_k<<<dim3(64, 8), 128, 0, stream>>>(attn, h1, ctxp);
  head_k<<<64, 64, 0, stream>>>(ctxp, d1w, d1b, ow, ob, (float*)d_out);
}

// Round 8
// 4746.379 us; speedup vs baseline: 3.2839x; 3.2839x over previous
//
#include <hip/hip_runtime.h>
#include <cstddef>

#define TT 4096
#define BB 64
#define HD 128
#define G4 512
#define FD 40
#define NCLS 12
#define CH 256
#define NCHUNK 16

typedef float v2f __attribute__((ext_vector_type(2)));

__device__ __forceinline__ float sigf(float x){ return 1.0f/(1.0f + __expf(-x)); }
__device__ __forceinline__ float tanh_f(float x){ return 1.0f - 2.0f/(__expf(2.0f*x) + 1.0f); }

// pack W_hh [512][128] -> WP float2[64][512]: WP[k2][j] = {W[j][2k2], W[j][2k2+1]}
__global__ void whh_pack(const float* __restrict__ W, float* __restrict__ WPf){
  int idx = blockIdx.x*256 + threadIdx.x;   // 32768 float2 elements
  int k2 = idx >> 9;
  int j  = idx & 511;
  float2 v = make_float2(W[j*HD + 2*k2], W[j*HD + 2*k2 + 1]);
  ((float2*)WPf)[idx] = v;
}

// Persistent recurrence, dual-layer capable.
// blocks [0,64): stream A; blocks [64,128): stream B. 512 threads, thread t owns gate row t.
// Weights: 64 float2 per thread (packed over k), inner product via v_pk_fma_f32.
__global__ __launch_bounds__(512, 2)
void lstm_rec_dual(const float* __restrict__ preA, const float* __restrict__ wpA,
                   float* __restrict__ houtA, float* __restrict__ stateA,
                   const float* __restrict__ preB, const float* __restrict__ wpB,
                   float* __restrict__ houtB, float* __restrict__ stateB,
                   int nsteps)
{
  int bb = blockIdx.x;
  const float* pre; const float* wpf; float* hout; float* state;
  if (bb < 64){ pre = preA; wpf = wpA; hout = houtA; state = stateA; }
  else        { pre = preB; wpf = wpB; hout = houtB; state = stateB; bb -= 64; }

  const int t = threadIdx.x;              // 0..511 = gate row
  __shared__ __align__(16) float h_lds[HD];
  __shared__ float g_lds[G4];

  const v2f* wp = (const v2f*)wpf;
  v2f w[64];
#pragma unroll
  for (int j=0;j<64;j++) w[j] = wp[j*512 + t];   // coalesced 8B loads

  float c = 0.0f;
  if (t < HD){
    h_lds[t] = state[bb*256 + t];
    c = state[bb*256 + 128 + t];
  }
  __syncthreads();   // one full sync at preamble is fine

  const float* prep = pre + (size_t)bb*G4 + t;
  float pg = prep[0];

  for (int s=0; s<nsteps; ++s){
    int sn = (s+1 < nsteps) ? (s+1) : s;
    float npg = prep[(size_t)sn*(BB*G4)];        // prefetch next step's pre-gate

    v2f acc0; acc0.x = pg; acc0.y = 0.0f;
    v2f acc1; acc1.x = 0.0f; acc1.y = 0.0f;
#pragma unroll
    for (int j=0;j<64;j+=2){
      float4 h4 = *(const float4*)&h_lds[j*2];   // uniform-address broadcast read
      v2f h01; h01.x = h4.x; h01.y = h4.y;
      v2f h23; h23.x = h4.z; h23.y = h4.w;
      acc0 = __builtin_elementwise_fma(w[j],   h01, acc0);
      acc1 = __builtin_elementwise_fma(w[j+1], h23, acc1);
    }
    float g = (acc0.x + acc1.x) + (acc0.y + acc1.y);

    g_lds[t] = g;
    asm volatile("s_waitcnt lgkmcnt(0)" ::: "memory");   // g writes visible
    __builtin_amdgcn_s_barrier();
    __builtin_amdgcn_sched_barrier(0);

    if (t < HD){
      float gi = g;                 // own row = gate i for h-index t
      float gf = g_lds[t + 128];
      float gg = g_lds[t + 256];
      float go = g_lds[t + 384];
      c = sigf(gf)*c + sigf(gi)*tanh_f(gg);
      float h = sigf(go)*tanh_f(c);
      h_lds[t] = h;
      hout[((size_t)s*BB + bb)*HD + t] = h;      // fire-and-forget (no vmcnt drain)
    }
    asm volatile("s_waitcnt lgkmcnt(0)" ::: "memory");   // h writes visible
    __builtin_amdgcn_s_barrier();
    __builtin_amdgcn_sched_barrier(0);

    pg = npg;
  }

  if (t < HD){
    state[bb*256 + t] = h_lds[t];
    state[bb*256 + 128 + t] = c;
  }
}

// Generic fp32 tiled GEMM: C[M x N] = A[M x K] * B(^T) + bias, tile 128x128x8, 8x8/thread.
// AMODE: 0 -> A row-major lda=KD; 1 -> A is x with layout [64][4096][40], row m=(t_local*64+b)
// BTRANS: 1 -> Bw is [N][K] (C=A*W^T); 0 -> Bw is [K][N]
// EPI: 0 -> C[m][n]=acc+b1[n]+b2[n] (N=512); 1 -> attn[m]=sum_n tanh(acc+b1[n])*b2[n] (N=128)
template<int AMODE, int BTRANS, int KD, int EPI>
__global__ __launch_bounds__(256)
void gemm_k(const float* __restrict__ A, const float* __restrict__ Bw,
            const float* __restrict__ b1, const float* __restrict__ b2,
            float* __restrict__ C, int t0)
{
  const int tid = threadIdx.x;
  const int tx = tid & 15, ty = tid >> 4;
  const int m0 = blockIdx.x * 128;
  const int n0 = blockIdx.y * 128;
  const int NDIM = EPI ? 128 : 512;
  __shared__ __align__(16) float Ast[8*128];
  __shared__ __align__(16) float Bst[8*128];
  __shared__ float red[128*17];
  float acc[8][8];
#pragma unroll
  for (int i=0;i<8;i++)
#pragma unroll
    for (int j=0;j<8;j++) acc[i][j]=0.f;

  const int NK = KD/8;
  for (int kt=0; kt<NK; ++kt){
    const int k0 = kt*8;
    const int arow = tid >> 1;
    const int akq = (tid & 1) * 4;
    const float* aptr;
    if (AMODE == 0){
      aptr = A + (size_t)(m0 + arow)*KD + k0 + akq;
    } else {
      int m = m0 + arow;
      int bidx = m & 63;
      int trow = t0 + (m >> 6);
      aptr = A + ((size_t)bidx*TT + trow)*FD + k0 + akq;
    }
    float4 av = *(const float4*)aptr;
    float4 bv;
    int brow, bkq;
    if (BTRANS){
      brow = tid >> 1; bkq = (tid & 1) * 4;
      bv = *(const float4*)(Bw + (size_t)(n0 + brow)*KD + k0 + bkq);
    } else {
      brow = tid >> 5;
      bkq = (tid & 31) * 4;
      bv = *(const float4*)(Bw + (size_t)(k0 + brow)*NDIM + n0 + bkq);
    }
    __syncthreads();
    Ast[(akq+0)*128 + arow] = av.x;
    Ast[(akq+1)*128 + arow] = av.y;
    Ast[(akq+2)*128 + arow] = av.z;
    Ast[(akq+3)*128 + arow] = av.w;
    if (BTRANS){
      Bst[(bkq+0)*128 + brow] = bv.x;
      Bst[(bkq+1)*128 + brow] = bv.y;
      Bst[(bkq+2)*128 + brow] = bv.z;
      Bst[(bkq+3)*128 + brow] = bv.w;
    } else {
      *(float4*)&Bst[brow*128 + bkq] = bv;
    }
    __syncthreads();
#pragma unroll
    for (int kk=0; kk<8; ++kk){
      float a[8], bbv[8];
      *(float4*)&a[0]   = *(const float4*)&Ast[kk*128 + ty*8];
      *(float4*)&a[4]   = *(const float4*)&Ast[kk*128 + ty*8 + 4];
      *(float4*)&bbv[0] = *(const float4*)&Bst[kk*128 + tx*8];
      *(float4*)&bbv[4] = *(const float4*)&Bst[kk*128 + tx*8 + 4];
#pragma unroll
      for (int i=0;i<8;i++)
#pragma unroll
        for (int j=0;j<8;j++) acc[i][j] = fmaf(a[i], bbv[j], acc[i][j]);
    }
  }
  if (EPI == 0){
    const int nb = n0 + tx*8;
    float bias[8];
#pragma unroll
    for (int j=0;j<8;j++) bias[j] = b1[nb+j] + b2[nb+j];
#pragma unroll
    for (int i=0;i<8;i++){
      int m = m0 + ty*8 + i;
      float* cp = C + (size_t)m*NDIM + nb;
      float4 o0 = make_float4(acc[i][0]+bias[0], acc[i][1]+bias[1], acc[i][2]+bias[2], acc[i][3]+bias[3]);
      float4 o1 = make_float4(acc[i][4]+bias[4], acc[i][5]+bias[5], acc[i][6]+bias[6], acc[i][7]+bias[7]);
      *(float4*)&cp[0] = o0;
      *(float4*)&cp[4] = o1;
    }
  } else {
    const int nb = tx*8;
    float bias[8], proj[8];
#pragma unroll
    for (int j=0;j<8;j++){ bias[j] = b1[nb+j]; proj[j] = b2[nb+j]; }
#pragma unroll
    for (int i=0;i<8;i++){
      float p = 0.f;
#pragma unroll
      for (int j=0;j<8;j++) p += tanh_f(acc[i][j] + bias[j]) * proj[j];
      red[(ty*8+i)*17 + tx] = p;
    }
    __syncthreads();
    if (tid < 128){
      float s = 0.f;
#pragma unroll
      for (int xx=0; xx<16; ++xx) s += red[tid*17 + xx];
      C[m0 + tid] = s;
    }
  }
}

// softmax over time per batch column; attn layout [T][B]
__global__ void softmax_t(float* __restrict__ attn){
  const int b = blockIdx.x;
  const int tid = threadIdx.x;   // 256
  __shared__ float red[256];
  float v[16];
  float m = -1e30f;
#pragma unroll
  for (int i=0;i<16;i++){
    v[i] = attn[(i*256 + tid)*BB + b];
    m = fmaxf(m, v[i]);
  }
  red[tid] = m; __syncthreads();
  for (int s=128; s>0; s>>=1){ if (tid < s) red[tid] = fmaxf(red[tid], red[tid+s]); __syncthreads(); }
  m = red[0]; __syncthreads();
  float sum = 0.f;
#pragma unroll
  for (int i=0;i<16;i++){ v[i] = __expf(v[i]-m); sum += v[i]; }
  red[tid] = sum; __syncthreads();
  for (int s=128; s>0; s>>=1){ if (tid < s) red[tid] += red[tid+s]; __syncthreads(); }
  float inv = 1.0f/red[0];
#pragma unroll
  for (int i=0;i<16;i++) attn[(i*256 + tid)*BB + b] = v[i]*inv;
}

// ctx partial: block (b, g): partial over 512 timesteps
__global__ void ctx_k(const float* __restrict__ attn, const float* __restrict__ h1,
                      float* __restrict__ ctxp){
  const int b = blockIdx.x;
  const int g = blockIdx.y;
  const int h = threadIdx.x;   // 128
  float acc = 0.f;
  const int tb = g*512;
#pragma unroll 4
  for (int i=0;i<512;i++){
    int t = tb + i;
    acc = fmaf(attn[t*BB + b], h1[((size_t)t*BB + b)*HD + h], acc);
  }
  ctxp[((size_t)b*8 + g)*HD + h] = acc;
}

__global__ void head_k(const float* __restrict__ ctxp, const float* __restrict__ d1w,
                       const float* __restrict__ d1b, const float* __restrict__ ow,
                       const float* __restrict__ ob, float* __restrict__ out){
  const int b = blockIdx.x;
  const int tid = threadIdx.x;  // 64
  __shared__ float cl[128];
  __shared__ float yl[64];
  for (int i=tid; i<128; i+=64){
    float s = 0.f;
#pragma unroll
    for (int g=0; g<8; g++) s += ctxp[((size_t)b*8 + g)*HD + i];
    cl[i] = s;
  }
  __syncthreads();
  float y = d1b[tid];
#pragma unroll 8
  for (int k=0;k<128;k++) y = fmaf(cl[k], d1w[tid*128 + k], y);
  yl[tid] = y;
  __syncthreads();
  if (tid < NCLS){
    float o = ob[tid];
#pragma unroll 8
    for (int j=0;j<64;j++) o = fmaf(yl[j], ow[tid*64 + j], o);
    out[b*NCLS + tid] = o;
  }
}

extern "C" void kernel_launch(void* const* d_in, const int* in_sizes, int n_in,
                              void* d_out, int out_size, void* d_ws, size_t ws_size,
                              hipStream_t stream) {
  const float* x     = (const float*)d_in[0];
  const float* Wih0  = (const float*)d_in[1];
  const float* Whh0  = (const float*)d_in[2];
  const float* bih0  = (const float*)d_in[3];
  const float* bhh0  = (const float*)d_in[4];
  const float* Wih1  = (const float*)d_in[5];
  const float* Whh1  = (const float*)d_in[6];
  const float* bih1  = (const float*)d_in[7];
  const float* bhh1  = (const float*)d_in[8];
  const float* wW    = (const float*)d_in[9];
  const float* bias  = (const float*)d_in[10];
  const float* proj  = (const float*)d_in[11];
  const float* d1w   = (const float*)d_in[12];
  const float* d1b   = (const float*)d_in[13];
  const float* ow    = (const float*)d_in[14];
  const float* ob    = (const float*)d_in[15];

  float* ws = (float*)d_ws;
  float* state0 = ws;                            // 16384
  float* state1 = state0 + 16384;                // 16384
  float* WP0    = state1 + 16384;                // 65536 (float2[64][512])
  float* WP1    = WP0 + 65536;                   // 65536
  float* pre0   = WP1 + 65536;                   // CH*64*512 = 8.39M
  float* pre1   = pre0 + (size_t)CH*BB*G4;       // 8.39M
  float* h0c    = pre1 + (size_t)CH*BB*G4;       // CH*64*128 = 2.10M
  float* h1     = h0c + (size_t)CH*BB*HD;        // T*64*128 = 33.55M
  float* attn   = h1 + (size_t)TT*BB*HD;         // T*64
  float* ctxp   = attn + (size_t)TT*BB;          // 64*8*128

  hipMemsetAsync(state0, 0, 2*16384*sizeof(float), stream);
  whh_pack<<<128, 256, 0, stream>>>(Whh0, WP0);
  whh_pack<<<128, 256, 0, stream>>>(Whh1, WP1);

  // pipeline: stage 0 = L0 chunk 0 alone
  gemm_k<1,1,40,0><<<dim3(CH*BB/128, 4), 256, 0, stream>>>(x, Wih0, bih0, bhh0, pre0, 0);
  lstm_rec_dual<<<64, 512, 0, stream>>>(pre0, WP0, h0c, state0,
                                        pre0, WP0, h0c, state0, CH);
  for (int k=1; k<NCHUNK; ++k){
    int t0A = (k-1)*CH;                          // layer1 chunk index
    int t0B = k*CH;                              // layer0 chunk index
    gemm_k<0,1,128,0><<<dim3(CH*BB/128, 4), 256, 0, stream>>>(h0c, Wih1, bih1, bhh1, pre1, 0);
    gemm_k<1,1,40,0><<<dim3(CH*BB/128, 4), 256, 0, stream>>>(x, Wih0, bih0, bhh0, pre0, t0B);
    lstm_rec_dual<<<128, 512, 0, stream>>>(pre1, WP1, h1 + (size_t)t0A*BB*HD, state1,
                                           pre0, WP0, h0c, state0, CH);
  }
  // tail: L1 chunk 15
  gemm_k<0,1,128,0><<<dim3(CH*BB/128, 4), 256, 0, stream>>>(h0c, Wih1, bih1, bhh1, pre1, 0);
  lstm_rec_dual<<<64, 512, 0, stream>>>(pre1, WP1, h1 + (size_t)(NCHUNK-1)*CH*BB*HD, state1,
                                        pre1, WP1, h1 + (size_t)(NCHUNK-1)*CH*BB*HD, state1, CH);

  // attention scores: attn[m] = sum_k tanh((h1 @ wW)[m,k] + bias[k]) * proj[k]
  gemm_k<0,0,128,1><<<dim3(TT*BB/128, 1), 256, 0, stream>>>(h1, wW, bias, proj, attn, 0);
  softmax_t<<<64, 256, 0, stream>>>(attn);
  ctx_k<<<dim3(64, 8), 128, 0, stream>>>(attn, h1, ctxp);
  head_k<<<64, 64, 0, stream>>>(ctxp, d1w, d1b, ow, ob, (float*)d_out);
}